// Round 4
// baseline (296.719 us; speedup 1.0000x reference)
//
#include <hip/hip_runtime.h>

#define N_NODES 10000
#define NE      80000
#define H       32
#define VD0     2048
#define VD1     256

// fixed-capacity edge buckets; overflow (deg > 32, never on this data) goes to
// an exact overflow list processed by the edge kernel's tail blocks
#define EDGE_CAP 32

// ---- prep dispatch: scatter blocks first (latency-bound, overlaps the
//      BW-bound normconv), then MLP, then normconv units --------------------
#define S_BLOCKS 313                       // ceil(NE/256) bucket-append blocks
#define A_MLP    40                        // node MLP, 256 nodes/block
#define A_NC0    2500                      // normconv graph0, 4 nodes/block
#define A_NC1    2500                      // normconv graph1, 4 nodes/block
#define PREP_BLOCKS (S_BLOCKS + A_MLP + A_NC0 + A_NC1)

// ---- edge dispatch -------------------------------------------------------
// graph0: 8 K-phases of 256 elems (512 B), phase = bid & 7 (XCD-pinned L2
// slices, R3: FETCH 143->70 MB). R4: one wave owns 10 dsts (amortize the
// cur->bucket->gather->reduce startup chain that made R3 slow), 16-deep
// predicated gather pipeline (covers deg<=16, 99.6%), next-dst prefetch.
#define E_G0BLK  2000                      // 8 phases x 250 blocks, 4 waves/blk
#define DPW0     10                        // dsts per wave, graph0 (1000 waves/phase)
#define E_G1BLK  500                       // graph1: 2000 waves x 5 dsts
#define DPW1     5
#define OVF_BLOCKS 16                      // exact overflow-list tail (normally empty)
#define EDGE_BLOCKS (E_G0BLK + E_G1BLK + OVF_BLOCKS)

// ---------------------------------------------------------------------------
// bf16 helpers
// ---------------------------------------------------------------------------
__device__ inline unsigned short f2bf_rne(float f) {
    unsigned int u = __float_as_uint(f);
    u += 0x7fffu + ((u >> 16) & 1u);
    return (unsigned short)(u >> 16);
}
__device__ inline float bflo(unsigned int u) { return __uint_as_float(u << 16); }
__device__ inline float bfhi(unsigned int u) { return __uint_as_float(u & 0xffff0000u); }

__device__ inline float dot8_bf16(uint4 a, uint4 b) {
    float s;
    s  = bflo(a.x) * bflo(b.x) + bfhi(a.x) * bfhi(b.x);
    s += bflo(a.y) * bflo(b.y) + bfhi(a.y) * bfhi(b.y);
    s += bflo(a.z) * bflo(b.z) + bfhi(a.z) * bfhi(b.z);
    s += bflo(a.w) * bflo(b.w) + bfhi(a.w) * bfhi(b.w);
    return s;
}
__device__ inline float dot4_bf16(uint2 a, uint2 b) {
    return bflo(a.x) * bflo(b.x) + bfhi(a.x) * bfhi(b.x)
         + bflo(a.y) * bflo(b.y) + bfhi(a.y) * bfhi(b.y);
}
// dst-row unpacked once per dst, reused across all 16 gathers
__device__ inline float dot4_pre(float a0, float a1, float a2, float a3, uint2 b) {
    return a0 * bflo(b.x) + a1 * bfhi(b.x) + a2 * bflo(b.y) + a3 * bfhi(b.y);
}

// ---------------------------------------------------------------------------
// param pack
// ---------------------------------------------------------------------------
struct KP {
    const float* x;
    const float* vis0; const float* vis1;
    const int* ei0; const int* ei1;
    const float* W_in1; const float* b_in1;
    const float* bn_gamma; const float* bn_beta;
    const float* bn_mean; const float* bn_var;
    const float* prelu_a;
    const float* W_in2; const float* b_in2;
    const float* w_node; const float* b_node;
    const float* W_c0; const float* b_c0;
    const float* W_c1; const float* b_c1;
    const float* w_p0; const float* b_p0;
    const float* w_p1; const float* b_p1;
    float* out; float* p0w; float* p1w;
    unsigned short* vn0; unsigned short* vn1;
    uint2* b0; uint2* b1;
    int2* ovf0; int2* ovf1;
    int* cur0; int* cur1; int* ovfn;   // cur0,cur1,ovfn CONTIGUOUS (one memset)
};

// ---------------------------------------------------------------------------
// normconv body: vn[node] = bf16( vis[node] * rsqrt(||vis[node]||^2 + 1e-8) )
// ---------------------------------------------------------------------------
template <int VD>
__device__ inline void normconv_node(const float* __restrict__ vis,
                                     unsigned short* __restrict__ vn,
                                     int node, int lane)
{
    const float4* v = (const float4*)(vis + (size_t)node * VD);
    float4 f[VD / 256];
    float acc = 0.f;
    #pragma unroll
    for (int it = 0; it < VD / 256; it++) {
        f[it] = v[it * 64 + lane];
        acc += f[it].x * f[it].x + f[it].y * f[it].y + f[it].z * f[it].z + f[it].w * f[it].w;
    }
    #pragma unroll
    for (int o = 32; o; o >>= 1) acc += __shfl_xor(acc, o);
    const float inv = rsqrtf(acc + 1e-8f);
    ushort4* o4 = (ushort4*)(vn + (size_t)node * VD);
    #pragma unroll
    for (int it = 0; it < VD / 256; it++) {
        ushort4 r;
        r.x = f2bf_rne(f[it].x * inv);
        r.y = f2bf_rne(f[it].y * inv);
        r.z = f2bf_rne(f[it].z * inv);
        r.w = f2bf_rne(f[it].w * inv);
        o4[it * 64 + lane] = r;
    }
}

// ---------------------------------------------------------------------------
// STAGE A unit: [0,40) node MLP; [40,2540) normconv0; [2540,5040) normconv1
// ---------------------------------------------------------------------------
__device__ inline void stageA_unit(const KP& p, int u, int t)
{
    if (u < A_MLP) {
        __shared__ float sW1[9 * H];
        __shared__ float sW2[H * H];
        __shared__ float sU0[H], sU1[H], sWn[H];
        __shared__ float sB1[H], sB2[H], sSc[H], sSh[H];
        __shared__ float sC;

        for (int i = t; i < 9 * H; i += 256) sW1[i] = p.W_in1[i];
        for (int i = t; i < H * H; i += 256) sW2[i] = p.W_in2[i];
        if (t < H) {
            sB1[t] = p.b_in1[t];
            sB2[t] = p.b_in2[t];
            float sc = p.bn_gamma[t] * rsqrtf(p.bn_var[t] + 1e-5f);
            sSc[t] = sc;
            sSh[t] = p.bn_beta[t] - p.bn_mean[t] * sc;
            sWn[t] = p.w_node[t];
            float u0 = 0.f, u1 = 0.f;
            for (int j = 0; j < H; j++) {
                u0 += p.W_c0[t * H + j] * p.w_p0[j];
                u1 += p.W_c1[t * H + j] * p.w_p1[j];
            }
            sU0[t] = u0; sU1[t] = u1;
        }
        if (t == 0) {
            float c0 = p.b_p0[0], c1 = p.b_p1[0];
            for (int j = 0; j < H; j++) { c0 += p.b_c0[j] * p.w_p0[j]; c1 += p.b_c1[j] * p.w_p1[j]; }
            sC = c0 + c1 + p.b_node[0];
        }
        __syncthreads();

        const float a = p.prelu_a[0];
        const int n = u * 256 + t;
        if (n < N_NODES) {
            float xi[9];
            #pragma unroll
            for (int i = 0; i < 9; i++) xi[i] = p.x[n * 9 + i];

            float tt[H];
            #pragma unroll
            for (int j = 0; j < H; j++) {
                float s = sB1[j];
                #pragma unroll
                for (int i = 0; i < 9; i++) s += xi[i] * sW1[i * H + j];
                s = s * sSc[j] + sSh[j];
                tt[j] = s >= 0.f ? s : a * s;
            }

            float ns = 0.f, p0 = 0.f, p1 = 0.f;
            #pragma unroll
            for (int k = 0; k < H; k++) {
                float h = sB2[k];
                #pragma unroll
                for (int j = 0; j < H; j++) h += tt[j] * sW2[j * H + k];
                ns += h * sWn[k];
                p0 += h * sU0[k];
                p1 += h * sU1[k];
            }
            p.out[n] = ns + sC;
            p.p0w[n] = p0;
            p.p1w[n] = p1;
        }
    } else if (u < A_MLP + A_NC0) {
        const int node = (u - A_MLP) * 4 + (t >> 6);
        normconv_node<VD0>(p.vis0, p.vn0, node, t & 63);
    } else {
        const int node = (u - A_MLP - A_NC0) * 4 + (t >> 6);
        normconv_node<VD1>(p.vis1, p.vn1, node, t & 63);
    }
}

// ---------------------------------------------------------------------------
// STAGE B: bucket append, one edge (both graphs). Entry = {row byte offset,
// src id}. Overflow -> exact list (processed in edge kernel tail).
// Depends only on ei + zeroed cur -> runs INSIDE prep, overlapped.
// ---------------------------------------------------------------------------
__device__ inline void stageB_edge(const KP& p, int e)
{
    {
        const int s = p.ei0[e];
        const int d = p.ei0[NE + e];
        const int pos = atomicAdd(&p.cur0[d], 1);
        if (pos < EDGE_CAP)
            p.b0[d * EDGE_CAP + pos] = make_uint2((unsigned)(s * (VD0 * 2)), (unsigned)s);
        else
            p.ovf0[atomicAdd(&p.ovfn[0], 1)] = make_int2(d, s);
    }
    {
        const int s = p.ei1[e];
        const int d = p.ei1[NE + e];
        const int pos = atomicAdd(&p.cur1[d], 1);
        if (pos < EDGE_CAP)
            p.b1[d * EDGE_CAP + pos] = make_uint2((unsigned)(s * (VD1 * 2)), (unsigned)s);
        else
            p.ovf1[atomicAdd(&p.ovfn[1], 1)] = make_int2(d, s);
    }
}

// ---------------------------------------------------------------------------
// 16-deep predicated gather chunk (entries j..j+15 of dst's bucket).
// Clamped slots gather vn[0] (safe) with pw forced 0. pw loads issue with the
// gathers and hoist freely (no stores in between).
// ---------------------------------------------------------------------------
__device__ inline float chunk16(const char* __restrict__ base,
                                const float* __restrict__ pwv,
                                const uint2* __restrict__ eb, int j, int c,
                                int koffB, float a0, float a1, float a2, float a3)
{
    uint2 e[16];
    #pragma unroll
    for (int k = 0; k < 16; k++) {
        uint2 tt = eb[j + k];
        e[k] = (j + k < c) ? tt : make_uint2(0u, 0u);
    }
    uint2 r[16];
    #pragma unroll
    for (int k = 0; k < 16; k++)
        r[k] = *(const uint2*)(base + e[k].x + koffB);
    float s = 0.f;
    #pragma unroll
    for (int k = 0; k < 16; k++) {
        float pw = pwv[e[k].y];
        pw = (j + k < c) ? pw : 0.f;
        s += dot4_pre(a0, a1, a2, a3, r[k]) * pw;
    }
    return s;
}

// ---------------------------------------------------------------------------
// STAGE C: multi-dst waves.
//  graph0 [0,2000): phase = bid&7 (XCD pin), wave owns DPW0 contiguous dsts.
//  graph1 [2000,2500): wave owns DPW1 dsts, full 512B rows.
//  [2500,2516): exact overflow-list tail (normally empty).
// ---------------------------------------------------------------------------
__global__ __launch_bounds__(256, 3) void edge3_kernel(KP p)
{
    const int bid  = blockIdx.x;
    const int t    = threadIdx.x;
    const int lane = t & 63;
    const int warp = t >> 6;

    if (bid < E_G0BLK) {
        const int phase = bid & 7;
        const int q     = bid >> 3;                 // 0..249
        const int wv    = q * 4 + warp;             // 0..999 within phase
        const int d0 = wv * DPW0, d1 = d0 + DPW0;
        const char* base = (const char*)p.vn0;
        const int koffB  = phase * 512 + lane * 8;

        int cnt = p.cur0[d0];
        uint2 dreg = *(const uint2*)(base + (size_t)d0 * (VD0 * 2) + koffB);
        for (int d = d0; d < d1; d++) {
            const int c = cnt < EDGE_CAP ? cnt : EDGE_CAP;
            const uint2* eb = p.b0 + (size_t)d * EDGE_CAP;
            // prefetch next dst meta (clamped index -> branchless, always issued)
            const int dn = (d + 1 < d1) ? d + 1 : d;
            const int cnt_n = p.cur0[dn];
            const uint2 dreg_n = *(const uint2*)(base + (size_t)dn * (VD0 * 2) + koffB);

            const float a0 = bflo(dreg.x), a1 = bfhi(dreg.x);
            const float a2 = bflo(dreg.y), a3 = bfhi(dreg.y);
            float partial = chunk16(base, p.p0w, eb, 0, c, koffB, a0, a1, a2, a3);
            if (c > 16)
                partial += chunk16(base, p.p0w, eb, 16, c, koffB, a0, a1, a2, a3);

            #pragma unroll
            for (int o = 32; o; o >>= 1) partial += __shfl_down(partial, o);
            if (lane == 0 && c > 0) atomicAdd(&p.out[d], partial);
            cnt = cnt_n; dreg = dreg_n;
        }
    } else if (bid < E_G0BLK + E_G1BLK) {
        const int wv = (bid - E_G0BLK) * 4 + warp;  // 0..1999
        const int d0 = wv * DPW1, d1 = d0 + DPW1;
        const char* base = (const char*)p.vn1;
        const int koffB  = lane * 8;

        int cnt = p.cur1[d0];
        uint2 dreg = *(const uint2*)(base + (size_t)d0 * (VD1 * 2) + koffB);
        for (int d = d0; d < d1; d++) {
            const int c = cnt < EDGE_CAP ? cnt : EDGE_CAP;
            const uint2* eb = p.b1 + (size_t)d * EDGE_CAP;
            const int dn = (d + 1 < d1) ? d + 1 : d;
            const int cnt_n = p.cur1[dn];
            const uint2 dreg_n = *(const uint2*)(base + (size_t)dn * (VD1 * 2) + koffB);

            const float a0 = bflo(dreg.x), a1 = bfhi(dreg.x);
            const float a2 = bflo(dreg.y), a3 = bfhi(dreg.y);
            float partial = chunk16(base, p.p1w, eb, 0, c, koffB, a0, a1, a2, a3);
            if (c > 16)
                partial += chunk16(base, p.p1w, eb, 16, c, koffB, a0, a1, a2, a3);

            #pragma unroll
            for (int o = 32; o; o >>= 1) partial += __shfl_down(partial, o);
            if (lane == 0 && c > 0) atomicAdd(&p.out[d], partial);
            cnt = cnt_n; dreg = dreg_n;
        }
    } else {
        // exact overflow tail (deg > EDGE_CAP edges; normally n0 = n1 = 0)
        const int wv = (bid - E_G0BLK - E_G1BLK) * 4 + warp;   // 0..63
        const int n0 = p.ovfn[0];
        for (int i = wv; i < n0; i += OVF_BLOCKS * 4) {
            const int2 ds = p.ovf0[i];
            const uint4* A = (const uint4*)(p.vn0 + (size_t)ds.y * VD0);
            const uint4* B = (const uint4*)(p.vn0 + (size_t)ds.x * VD0);
            float acc = 0.f;
            #pragma unroll
            for (int it = 0; it < 4; it++)
                acc += dot8_bf16(A[it * 64 + lane], B[it * 64 + lane]);
            #pragma unroll
            for (int o = 32; o; o >>= 1) acc += __shfl_down(acc, o);
            if (lane == 0) atomicAdd(&p.out[ds.x], acc * p.p0w[ds.y]);
        }
        const int n1 = p.ovfn[1];
        for (int i = wv; i < n1; i += OVF_BLOCKS * 4) {
            const int2 ds = p.ovf1[i];
            const uint2* A = (const uint2*)(p.vn1 + (size_t)ds.y * VD1);
            const uint2* B = (const uint2*)(p.vn1 + (size_t)ds.x * VD1);
            float acc = dot4_bf16(A[lane], B[lane]);
            #pragma unroll
            for (int o = 32; o; o >>= 1) acc += __shfl_down(acc, o);
            if (lane == 0) atomicAdd(&p.out[ds.x], acc * p.p1w[ds.y]);
        }
    }
}

// ---------------------------------------------------------------------------
// PREP: scatter blocks first (latency-bound, overlap), then stage A units
// ---------------------------------------------------------------------------
__global__ __launch_bounds__(256) void prep3_kernel(KP p)
{
    const int b = blockIdx.x, t = threadIdx.x;
    if (b < S_BLOCKS) {
        const int e = b * 256 + t;
        if (e < NE) stageB_edge(p, e);
    } else {
        stageA_unit(p, b - S_BLOCKS, t);
    }
}

// ---------------------------------------------------------------------------
// fp32 minimal fallback (only if ws can't hold bf16 rows + buckets)
// ---------------------------------------------------------------------------
template <int VD>
__global__ __launch_bounds__(256) void norm_kernel(const float* __restrict__ vis,
                                                   float* __restrict__ inv)
{
    const int wave = (blockIdx.x * 256 + threadIdx.x) >> 6;
    const int lane = threadIdx.x & 63;
    if (wave >= N_NODES) return;
    const float4* v = (const float4*)(vis + (size_t)wave * VD);
    float acc = 0.f;
    #pragma unroll
    for (int it = 0; it < VD / 256; it++) {
        float4 f = v[lane + it * 64];
        acc += f.x * f.x + f.y * f.y + f.z * f.z + f.w * f.w;
    }
    #pragma unroll
    for (int o = 32; o; o >>= 1) acc += __shfl_down(acc, o);
    if (lane == 0) inv[wave] = rsqrtf(acc + 1e-8f);
}

template <int VD>
__global__ __launch_bounds__(256) void edge_kernel(
    const float* __restrict__ vis, const int* __restrict__ ei,
    const float* __restrict__ inv, const float* __restrict__ pz,
    float* __restrict__ out)
{
    const int wave = (blockIdx.x * 256 + threadIdx.x) >> 6;
    const int lane = threadIdx.x & 63;
    if (wave >= NE) return;
    const int src = ei[wave];
    const int dst = ei[NE + wave];
    const float4* va = (const float4*)(vis + (size_t)src * VD);
    const float4* vb = (const float4*)(vis + (size_t)dst * VD);
    float acc = 0.f;
    #pragma unroll
    for (int it = 0; it < VD / 256; it++) {
        float4 fa = va[lane + it * 64];
        float4 fb = vb[lane + it * 64];
        acc += fa.x * fb.x + fa.y * fb.y + fa.z * fb.z + fa.w * fb.w;
    }
    #pragma unroll
    for (int o = 32; o; o >>= 1) acc += __shfl_down(acc, o);
    if (lane == 0) {
        float w = acc * inv[src] * inv[dst];
        atomicAdd(&out[dst], w * pz[src]);
    }
}

__global__ __launch_bounds__(256) void node_kernel_fb(KP p)
{
    stageA_unit(p, (int)blockIdx.x, (int)threadIdx.x);  // only MLP units launched
}

extern "C" void kernel_launch(void* const* d_in, const int* in_sizes, int n_in,
                              void* d_out, int out_size, void* d_ws, size_t ws_size,
                              hipStream_t stream)
{
    KP hp;
    hp.x        = (const float*)d_in[0];
    hp.vis0     = (const float*)d_in[1];
    hp.vis1     = (const float*)d_in[2];
    hp.ei0      = (const int*)d_in[3];
    hp.ei1      = (const int*)d_in[4];
    hp.W_in1    = (const float*)d_in[5];
    hp.b_in1    = (const float*)d_in[6];
    hp.bn_gamma = (const float*)d_in[7];
    hp.bn_beta  = (const float*)d_in[8];
    hp.bn_mean  = (const float*)d_in[9];
    hp.bn_var   = (const float*)d_in[10];
    hp.prelu_a  = (const float*)d_in[11];
    hp.W_in2    = (const float*)d_in[12];
    hp.b_in2    = (const float*)d_in[13];
    hp.w_node   = (const float*)d_in[14];
    hp.b_node   = (const float*)d_in[15];
    hp.W_c0     = (const float*)d_in[16];
    hp.b_c0     = (const float*)d_in[17];
    hp.W_c1     = (const float*)d_in[18];
    hp.b_c1     = (const float*)d_in[19];
    hp.w_p0     = (const float*)d_in[20];
    hp.b_p0     = (const float*)d_in[21];
    hp.w_p1     = (const float*)d_in[22];
    hp.b_p1     = (const float*)d_in[23];
    hp.out      = (float*)d_out;

    // workspace layout — small arrays FIRST (fp32 fallback needs ~160 KB),
    // every chunk a multiple of 16 B
    char* ws = (char*)d_ws;
    hp.p0w  = (float*)ws;                  ws += N_NODES * 4;
    hp.p1w  = (float*)ws;                  ws += N_NODES * 4;
    float* inv0 = (float*)ws;              ws += N_NODES * 4;
    float* inv1 = (float*)ws;              ws += N_NODES * 4;
    hp.vn0  = (unsigned short*)ws;         ws += (size_t)N_NODES * VD0 * 2;
    hp.vn1  = (unsigned short*)ws;         ws += (size_t)N_NODES * VD1 * 2;
    hp.b0   = (uint2*)ws;                  ws += (size_t)N_NODES * EDGE_CAP * 8;
    hp.b1   = (uint2*)ws;                  ws += (size_t)N_NODES * EDGE_CAP * 8;
    hp.ovf0 = (int2*)ws;                   ws += (size_t)NE * 8;
    hp.ovf1 = (int2*)ws;                   ws += (size_t)NE * 8;
    hp.cur0 = (int*)ws;                    ws += N_NODES * 4;   // cur0,cur1,ovfn
    hp.cur1 = (int*)ws;                    ws += N_NODES * 4;   //   contiguous:
    hp.ovfn = (int*)ws;                    ws += 16;            //   one memset
    const size_t need = (size_t)(ws - (char*)d_ws);

    if (ws_size >= need) {
        hipMemsetAsync(hp.cur0, 0, 2 * N_NODES * sizeof(int) + 16, stream);
        prep3_kernel<<<PREP_BLOCKS, 256, 0, stream>>>(hp);
        edge3_kernel<<<EDGE_BLOCKS, 256, 0, stream>>>(hp);
    } else {
        // fp32 minimal-workspace fallback
        node_kernel_fb<<<A_MLP, 256, 0, stream>>>(hp);
        norm_kernel<VD0><<<(N_NODES * 64 + 255) / 256, 256, 0, stream>>>(hp.vis0, inv0);
        norm_kernel<VD1><<<(N_NODES * 64 + 255) / 256, 256, 0, stream>>>(hp.vis1, inv1);
        edge_kernel<VD0><<<(NE * 64 + 255) / 256, 256, 0, stream>>>(hp.vis0, hp.ei0, inv0, hp.p0w, hp.out);
        edge_kernel<VD1><<<(NE * 64 + 255) / 256, 256, 0, stream>>>(hp.vis1, hp.ei1, inv1, hp.p1w, hp.out);
    }
}

// Round 5
// 210.254 us; speedup vs baseline: 1.4112x; 1.4112x over previous
//
#include <hip/hip_runtime.h>

#define N_NODES 10000
#define NE      80000
#define H       32
#define VD0     2048
#define VD1     256

// fixed-capacity edge buckets; overflow (deg > 32, never on this data) goes to
// an exact overflow list processed by the edge kernel's tail blocks
#define EDGE_CAP 32

// ---- prep dispatch: scatter blocks first (latency-bound, overlaps the
//      BW-bound normconv), then MLP, then normconv units --------------------
#define S_BLOCKS 313                       // ceil(NE/256) bucket-append blocks
#define A_MLP    40                        // node MLP, 256 nodes/block
#define A_NC0    2500                      // normconv+quant graph0, 4 nodes/blk
#define A_NC1    2500                      // normconv+quant graph1, 4 nodes/blk
#define PREP_BLOCKS (S_BLOCKS + A_MLP + A_NC0 + A_NC1)

// ---- edge dispatch -------------------------------------------------------
// R5: int8 rows (per-row scale, exact i32 dot). Edge stage reverts to the
// R1-proven shape: wave per (dst,phase), 4-edge unroll, 16B/lane gathers.
// graph0: 2 phases x 1024 int8 elems (1KB gathers), 2500 groups x 4 dsts.
// graph1: wave per dst, full 256B row (4B/lane).
#define E0_BLOCKS 5000                     // 2 phases x 2500 groups
#define E1_BLOCKS 2500
#define OVF_BLOCKS 16                      // exact overflow tail (normally empty)
#define EDGE_BLOCKS (E0_BLOCKS + E1_BLOCKS + OVF_BLOCKS)

// ---------------------------------------------------------------------------
// int8 dot helpers (v_dot4_i32_i8 when available, exact manual fallback)
// ---------------------------------------------------------------------------
__device__ inline int dot4i8(unsigned a, unsigned b, int c) {
#if __has_builtin(__builtin_amdgcn_sdot4)
    return __builtin_amdgcn_sdot4((int)a, (int)b, c, false);
#else
    int s = c;
    s += ((int)(a << 24) >> 24) * ((int)(b << 24) >> 24);
    s += ((int)(a << 16) >> 24) * ((int)(b << 16) >> 24);
    s += ((int)(a <<  8) >> 24) * ((int)(b <<  8) >> 24);
    s += ((int)a >> 24)         * ((int)b >> 24);
    return s;
#endif
}
__device__ inline int dot16i8(uint4 a, uint4 b, int c) {
    c = dot4i8(a.x, b.x, c);
    c = dot4i8(a.y, b.y, c);
    c = dot4i8(a.z, b.z, c);
    c = dot4i8(a.w, b.w, c);
    return c;
}

// ---------------------------------------------------------------------------
// param pack
// ---------------------------------------------------------------------------
struct KP {
    const float* x;
    const float* vis0; const float* vis1;
    const int* ei0; const int* ei1;
    const float* W_in1; const float* b_in1;
    const float* bn_gamma; const float* bn_beta;
    const float* bn_mean; const float* bn_var;
    const float* prelu_a;
    const float* W_in2; const float* b_in2;
    const float* w_node; const float* b_node;
    const float* W_c0; const float* b_c0;
    const float* W_c1; const float* b_c1;
    const float* w_p0; const float* b_p0;
    const float* w_p1; const float* b_p1;
    float* out; float* p0w; float* p1w;
    signed char* vn0; signed char* vn1;    // int8 normalized rows
    float* s00; float* s01;                // per-row dequant scales
    uint2* b0; uint2* b1;
    int2* ovf0; int2* ovf1;
    int* cur0; int* cur1; int* ovfn;   // cur0,cur1,ovfn CONTIGUOUS (one memset)
};

// ---------------------------------------------------------------------------
// normconv+quant: v = vis[node] * rsqrt(||.||^2 + 1e-8); q = rint(v*127/vmax)
// stored int8; s0[node] = vmax/127 so v ~= q * s0. Exact i32 dot later ->
// only input-quantization noise. One wave per node, row held in registers.
// ---------------------------------------------------------------------------
template <int VD>
__device__ inline void normconv_q_node(const float* __restrict__ vis,
                                       signed char* __restrict__ vn,
                                       float* __restrict__ s0,
                                       int node, int lane)
{
    const float4* v = (const float4*)(vis + (size_t)node * VD);
    float4 f[VD / 256];
    float acc = 0.f, amax = 0.f;
    #pragma unroll
    for (int it = 0; it < VD / 256; it++) {
        f[it] = v[it * 64 + lane];
        acc += f[it].x * f[it].x + f[it].y * f[it].y
             + f[it].z * f[it].z + f[it].w * f[it].w;
        float m = fmaxf(fmaxf(fabsf(f[it].x), fabsf(f[it].y)),
                        fmaxf(fabsf(f[it].z), fabsf(f[it].w)));
        amax = fmaxf(amax, m);
    }
    #pragma unroll
    for (int o = 32; o; o >>= 1) {
        acc  += __shfl_xor(acc, o);
        amax  = fmaxf(amax, __shfl_xor(amax, o));
    }
    const float inv  = rsqrtf(acc + 1e-8f);
    const float vmax = amax * inv;                 // max |normalized elem|
    const float k    = vmax > 0.f ? inv * (127.f / vmax) : 0.f;
    if (lane == 0) s0[node] = vmax * (1.f / 127.f);
    uint* o4 = (uint*)(vn + (size_t)node * VD);
    #pragma unroll
    for (int it = 0; it < VD / 256; it++) {
        const int q0 = (int)rintf(f[it].x * k);
        const int q1 = (int)rintf(f[it].y * k);
        const int q2 = (int)rintf(f[it].z * k);
        const int q3 = (int)rintf(f[it].w * k);
        o4[it * 64 + lane] = (unsigned)(q0 & 0xff)
                           | ((unsigned)(q1 & 0xff) << 8)
                           | ((unsigned)(q2 & 0xff) << 16)
                           | ((unsigned)(q3 & 0xff) << 24);
    }
}

// ---------------------------------------------------------------------------
// STAGE A unit: [0,40) node MLP; [40,2540) quantconv0; [2540,5040) quantconv1
// ---------------------------------------------------------------------------
__device__ inline void stageA_unit(const KP& p, int u, int t)
{
    if (u < A_MLP) {
        __shared__ float sW1[9 * H];
        __shared__ float sW2[H * H];
        __shared__ float sU0[H], sU1[H], sWn[H];
        __shared__ float sB1[H], sB2[H], sSc[H], sSh[H];
        __shared__ float sC;

        for (int i = t; i < 9 * H; i += 256) sW1[i] = p.W_in1[i];
        for (int i = t; i < H * H; i += 256) sW2[i] = p.W_in2[i];
        if (t < H) {
            sB1[t] = p.b_in1[t];
            sB2[t] = p.b_in2[t];
            float sc = p.bn_gamma[t] * rsqrtf(p.bn_var[t] + 1e-5f);
            sSc[t] = sc;
            sSh[t] = p.bn_beta[t] - p.bn_mean[t] * sc;
            sWn[t] = p.w_node[t];
            float u0 = 0.f, u1 = 0.f;
            for (int j = 0; j < H; j++) {
                u0 += p.W_c0[t * H + j] * p.w_p0[j];
                u1 += p.W_c1[t * H + j] * p.w_p1[j];
            }
            sU0[t] = u0; sU1[t] = u1;
        }
        if (t == 0) {
            float c0 = p.b_p0[0], c1 = p.b_p1[0];
            for (int j = 0; j < H; j++) { c0 += p.b_c0[j] * p.w_p0[j]; c1 += p.b_c1[j] * p.w_p1[j]; }
            sC = c0 + c1 + p.b_node[0];
        }
        __syncthreads();

        const float a = p.prelu_a[0];
        const int n = u * 256 + t;
        if (n < N_NODES) {
            float xi[9];
            #pragma unroll
            for (int i = 0; i < 9; i++) xi[i] = p.x[n * 9 + i];

            float tt[H];
            #pragma unroll
            for (int j = 0; j < H; j++) {
                float s = sB1[j];
                #pragma unroll
                for (int i = 0; i < 9; i++) s += xi[i] * sW1[i * H + j];
                s = s * sSc[j] + sSh[j];
                tt[j] = s >= 0.f ? s : a * s;
            }

            float ns = 0.f, p0 = 0.f, p1 = 0.f;
            #pragma unroll
            for (int k = 0; k < H; k++) {
                float h = sB2[k];
                #pragma unroll
                for (int j = 0; j < H; j++) h += tt[j] * sW2[j * H + k];
                ns += h * sWn[k];
                p0 += h * sU0[k];
                p1 += h * sU1[k];
            }
            p.out[n] = ns + sC;
            p.p0w[n] = p0;
            p.p1w[n] = p1;
        }
    } else if (u < A_MLP + A_NC0) {
        const int node = (u - A_MLP) * 4 + (t >> 6);
        normconv_q_node<VD0>(p.vis0, p.vn0, p.s00, node, t & 63);
    } else {
        const int node = (u - A_MLP - A_NC0) * 4 + (t >> 6);
        normconv_q_node<VD1>(p.vis1, p.vn1, p.s01, node, t & 63);
    }
}

// ---------------------------------------------------------------------------
// STAGE B: bucket append, one edge (both graphs). Entry = {row byte offset,
// src id}. Overflow -> exact list (processed in edge kernel tail).
// ---------------------------------------------------------------------------
__device__ inline void stageB_edge(const KP& p, int e)
{
    {
        const int s = p.ei0[e];
        const int d = p.ei0[NE + e];
        const int pos = atomicAdd(&p.cur0[d], 1);
        if (pos < EDGE_CAP)
            p.b0[d * EDGE_CAP + pos] = make_uint2((unsigned)(s * VD0), (unsigned)s);
        else
            p.ovf0[atomicAdd(&p.ovfn[0], 1)] = make_int2(d, s);
    }
    {
        const int s = p.ei1[e];
        const int d = p.ei1[NE + e];
        const int pos = atomicAdd(&p.cur1[d], 1);
        if (pos < EDGE_CAP)
            p.b1[d * EDGE_CAP + pos] = make_uint2((unsigned)(s * VD1), (unsigned)s);
        else
            p.ovf1[atomicAdd(&p.ovfn[1], 1)] = make_int2(d, s);
    }
}

// ---------------------------------------------------------------------------
// STAGE C: R1-proven shape on int8 rows.
//  graph0 [0,5000): phase = bid&1, 4 dsts/block, wave per dst, uint4/lane
//                   (16 int8 elems), 4-edge unroll.
//  graph1 [5000,7500): 4 dsts/block, wave per dst, full row, uint/lane.
//  [7500,7516): exact overflow tail.
// ---------------------------------------------------------------------------
__global__ __launch_bounds__(256) void edge4_kernel(KP p)
{
    const int bid  = blockIdx.x;
    const int t    = threadIdx.x;
    const int lane = t & 63;
    const int warp = t >> 6;

    if (bid < E0_BLOCKS) {
        const int phase = bid & 1;
        const int d     = (bid >> 1) * 4 + warp;
        int cnt = p.cur0[d];
        if (cnt <= 0) return;
        cnt = cnt < EDGE_CAP ? cnt : EDGE_CAP;

        const char* base = (const char*)p.vn0;
        const int koffB  = phase * 1024 + lane * 16;
        const uint4 dreg = *(const uint4*)(base + (size_t)d * VD0 + koffB);
        const uint2* eb  = p.b0 + (size_t)d * EDGE_CAP;

        float partial = 0.f;
        int j = 0;
        for (; j + 3 < cnt; j += 4) {
            const uint2 e0 = eb[j], e1 = eb[j + 1], e2 = eb[j + 2], e3 = eb[j + 3];
            const uint4 r0 = *(const uint4*)(base + e0.x + koffB);
            const uint4 r1 = *(const uint4*)(base + e1.x + koffB);
            const uint4 r2 = *(const uint4*)(base + e2.x + koffB);
            const uint4 r3 = *(const uint4*)(base + e3.x + koffB);
            const float w0 = p.p0w[e0.y] * p.s00[e0.y];
            const float w1 = p.p0w[e1.y] * p.s00[e1.y];
            const float w2 = p.p0w[e2.y] * p.s00[e2.y];
            const float w3 = p.p0w[e3.y] * p.s00[e3.y];
            partial += (float)dot16i8(dreg, r0, 0) * w0;
            partial += (float)dot16i8(dreg, r1, 0) * w1;
            partial += (float)dot16i8(dreg, r2, 0) * w2;
            partial += (float)dot16i8(dreg, r3, 0) * w3;
        }
        for (; j < cnt; j++) {
            const uint2 e0 = eb[j];
            const uint4 r0 = *(const uint4*)(base + e0.x + koffB);
            partial += (float)dot16i8(dreg, r0, 0) * (p.p0w[e0.y] * p.s00[e0.y]);
        }
        #pragma unroll
        for (int o = 32; o; o >>= 1) partial += __shfl_down(partial, o);
        if (lane == 0) atomicAdd(&p.out[d], partial * p.s00[d]);
    } else if (bid < E0_BLOCKS + E1_BLOCKS) {
        const int d = (bid - E0_BLOCKS) * 4 + warp;
        int cnt = p.cur1[d];
        if (cnt <= 0) return;
        cnt = cnt < EDGE_CAP ? cnt : EDGE_CAP;

        const char* base = (const char*)p.vn1;
        const int koffB  = lane * 4;
        const unsigned dreg = *(const unsigned*)(base + (size_t)d * VD1 + koffB);
        const uint2* eb  = p.b1 + (size_t)d * EDGE_CAP;

        float partial = 0.f;
        int j = 0;
        for (; j + 3 < cnt; j += 4) {
            const uint2 e0 = eb[j], e1 = eb[j + 1], e2 = eb[j + 2], e3 = eb[j + 3];
            const unsigned r0 = *(const unsigned*)(base + e0.x + koffB);
            const unsigned r1 = *(const unsigned*)(base + e1.x + koffB);
            const unsigned r2 = *(const unsigned*)(base + e2.x + koffB);
            const unsigned r3 = *(const unsigned*)(base + e3.x + koffB);
            const float w0 = p.p1w[e0.y] * p.s01[e0.y];
            const float w1 = p.p1w[e1.y] * p.s01[e1.y];
            const float w2 = p.p1w[e2.y] * p.s01[e2.y];
            const float w3 = p.p1w[e3.y] * p.s01[e3.y];
            partial += (float)dot4i8(dreg, r0, 0) * w0;
            partial += (float)dot4i8(dreg, r1, 0) * w1;
            partial += (float)dot4i8(dreg, r2, 0) * w2;
            partial += (float)dot4i8(dreg, r3, 0) * w3;
        }
        for (; j < cnt; j++) {
            const uint2 e0 = eb[j];
            const unsigned r0 = *(const unsigned*)(base + e0.x + koffB);
            partial += (float)dot4i8(dreg, r0, 0) * (p.p1w[e0.y] * p.s01[e0.y]);
        }
        #pragma unroll
        for (int o = 32; o; o >>= 1) partial += __shfl_down(partial, o);
        if (lane == 0) atomicAdd(&p.out[d], partial * p.s01[d]);
    } else {
        // exact overflow tail (deg > EDGE_CAP; normally empty)
        const int wv = (bid - E0_BLOCKS - E1_BLOCKS) * 4 + warp;
        const int n0 = p.ovfn[0];
        for (int i = wv; i < n0; i += OVF_BLOCKS * 4) {
            const int2 ds = p.ovf0[i];    // (dst, src)
            const uint4* A = (const uint4*)(p.vn0 + (size_t)ds.y * VD0);
            const uint4* B = (const uint4*)(p.vn0 + (size_t)ds.x * VD0);
            int id = 0;
            id = dot16i8(A[lane * 2],     B[lane * 2],     id);
            id = dot16i8(A[lane * 2 + 1], B[lane * 2 + 1], id);
            float acc = (float)id;
            #pragma unroll
            for (int o = 32; o; o >>= 1) acc += __shfl_down(acc, o);
            if (lane == 0)
                atomicAdd(&p.out[ds.x],
                          acc * p.s00[ds.y] * p.s00[ds.x] * p.p0w[ds.y]);
        }
        const int n1 = p.ovfn[1];
        for (int i = wv; i < n1; i += OVF_BLOCKS * 4) {
            const int2 ds = p.ovf1[i];
            const unsigned* A = (const unsigned*)(p.vn1 + (size_t)ds.y * VD1);
            const unsigned* B = (const unsigned*)(p.vn1 + (size_t)ds.x * VD1);
            float acc = (float)dot4i8(A[lane], B[lane], 0);
            #pragma unroll
            for (int o = 32; o; o >>= 1) acc += __shfl_down(acc, o);
            if (lane == 0)
                atomicAdd(&p.out[ds.x],
                          acc * p.s01[ds.y] * p.s01[ds.x] * p.p1w[ds.y]);
        }
    }
}

// ---------------------------------------------------------------------------
// PREP: scatter blocks first (latency-bound, overlap), then stage A units
// ---------------------------------------------------------------------------
__global__ __launch_bounds__(256) void prep4_kernel(KP p)
{
    const int b = blockIdx.x, t = threadIdx.x;
    if (b < S_BLOCKS) {
        const int e = b * 256 + t;
        if (e < NE) stageB_edge(p, e);
    } else {
        stageA_unit(p, b - S_BLOCKS, t);
    }
}

// ---------------------------------------------------------------------------
// fp32 minimal fallback (only if ws can't hold int8 rows + buckets)
// ---------------------------------------------------------------------------
template <int VD>
__global__ __launch_bounds__(256) void norm_kernel(const float* __restrict__ vis,
                                                   float* __restrict__ inv)
{
    const int wave = (blockIdx.x * 256 + threadIdx.x) >> 6;
    const int lane = threadIdx.x & 63;
    if (wave >= N_NODES) return;
    const float4* v = (const float4*)(vis + (size_t)wave * VD);
    float acc = 0.f;
    #pragma unroll
    for (int it = 0; it < VD / 256; it++) {
        float4 f = v[lane + it * 64];
        acc += f.x * f.x + f.y * f.y + f.z * f.z + f.w * f.w;
    }
    #pragma unroll
    for (int o = 32; o; o >>= 1) acc += __shfl_down(acc, o);
    if (lane == 0) inv[wave] = rsqrtf(acc + 1e-8f);
}

template <int VD>
__global__ __launch_bounds__(256) void edge_kernel(
    const float* __restrict__ vis, const int* __restrict__ ei,
    const float* __restrict__ inv, const float* __restrict__ pz,
    float* __restrict__ out)
{
    const int wave = (blockIdx.x * 256 + threadIdx.x) >> 6;
    const int lane = threadIdx.x & 63;
    if (wave >= NE) return;
    const int src = ei[wave];
    const int dst = ei[NE + wave];
    const float4* va = (const float4*)(vis + (size_t)src * VD);
    const float4* vb = (const float4*)(vis + (size_t)dst * VD);
    float acc = 0.f;
    #pragma unroll
    for (int it = 0; it < VD / 256; it++) {
        float4 fa = va[lane + it * 64];
        float4 fb = vb[lane + it * 64];
        acc += fa.x * fb.x + fa.y * fb.y + fa.z * fb.z + fa.w * fb.w;
    }
    #pragma unroll
    for (int o = 32; o; o >>= 1) acc += __shfl_down(acc, o);
    if (lane == 0) {
        float w = acc * inv[src] * inv[dst];
        atomicAdd(&out[dst], w * pz[src]);
    }
}

__global__ __launch_bounds__(256) void node_kernel_fb(KP p)
{
    stageA_unit(p, (int)blockIdx.x, (int)threadIdx.x);  // only MLP units launched
}

extern "C" void kernel_launch(void* const* d_in, const int* in_sizes, int n_in,
                              void* d_out, int out_size, void* d_ws, size_t ws_size,
                              hipStream_t stream)
{
    KP hp;
    hp.x        = (const float*)d_in[0];
    hp.vis0     = (const float*)d_in[1];
    hp.vis1     = (const float*)d_in[2];
    hp.ei0      = (const int*)d_in[3];
    hp.ei1      = (const int*)d_in[4];
    hp.W_in1    = (const float*)d_in[5];
    hp.b_in1    = (const float*)d_in[6];
    hp.bn_gamma = (const float*)d_in[7];
    hp.bn_beta  = (const float*)d_in[8];
    hp.bn_mean  = (const float*)d_in[9];
    hp.bn_var   = (const float*)d_in[10];
    hp.prelu_a  = (const float*)d_in[11];
    hp.W_in2    = (const float*)d_in[12];
    hp.b_in2    = (const float*)d_in[13];
    hp.w_node   = (const float*)d_in[14];
    hp.b_node   = (const float*)d_in[15];
    hp.W_c0     = (const float*)d_in[16];
    hp.b_c0     = (const float*)d_in[17];
    hp.W_c1     = (const float*)d_in[18];
    hp.b_c1     = (const float*)d_in[19];
    hp.w_p0     = (const float*)d_in[20];
    hp.b_p0     = (const float*)d_in[21];
    hp.w_p1     = (const float*)d_in[22];
    hp.b_p1     = (const float*)d_in[23];
    hp.out      = (float*)d_out;

    // workspace layout — small arrays FIRST (fp32 fallback needs ~160 KB),
    // every chunk a multiple of 16 B
    char* ws = (char*)d_ws;
    hp.p0w  = (float*)ws;                  ws += N_NODES * 4;
    hp.p1w  = (float*)ws;                  ws += N_NODES * 4;
    float* inv0 = (float*)ws;              ws += N_NODES * 4;
    float* inv1 = (float*)ws;              ws += N_NODES * 4;
    hp.s00  = (float*)ws;                  ws += N_NODES * 4;
    hp.s01  = (float*)ws;                  ws += N_NODES * 4;
    hp.vn0  = (signed char*)ws;            ws += (size_t)N_NODES * VD0;
    hp.vn1  = (signed char*)ws;            ws += (size_t)N_NODES * VD1;
    hp.b0   = (uint2*)ws;                  ws += (size_t)N_NODES * EDGE_CAP * 8;
    hp.b1   = (uint2*)ws;                  ws += (size_t)N_NODES * EDGE_CAP * 8;
    hp.ovf0 = (int2*)ws;                   ws += (size_t)NE * 8;
    hp.ovf1 = (int2*)ws;                   ws += (size_t)NE * 8;
    hp.cur0 = (int*)ws;                    ws += N_NODES * 4;   // cur0,cur1,ovfn
    hp.cur1 = (int*)ws;                    ws += N_NODES * 4;   //   contiguous:
    hp.ovfn = (int*)ws;                    ws += 16;            //   one memset
    const size_t need = (size_t)(ws - (char*)d_ws);

    if (ws_size >= need) {
        hipMemsetAsync(hp.cur0, 0, 2 * N_NODES * sizeof(int) + 16, stream);
        prep4_kernel<<<PREP_BLOCKS, 256, 0, stream>>>(hp);
        edge4_kernel<<<EDGE_BLOCKS, 256, 0, stream>>>(hp);
    } else {
        // fp32 minimal-workspace fallback
        node_kernel_fb<<<A_MLP, 256, 0, stream>>>(hp);
        norm_kernel<VD0><<<(N_NODES * 64 + 255) / 256, 256, 0, stream>>>(hp.vis0, inv0);
        norm_kernel<VD1><<<(N_NODES * 64 + 255) / 256, 256, 0, stream>>>(hp.vis1, inv1);
        edge_kernel<VD0><<<(NE * 64 + 255) / 256, 256, 0, stream>>>(hp.vis0, hp.ei0, inv0, hp.p0w, hp.out);
        edge_kernel<VD1><<<(NE * 64 + 255) / 256, 256, 0, stream>>>(hp.vis1, hp.ei1, inv1, hp.p1w, hp.out);
    }
}